// Round 4
// baseline (12396.247 us; speedup 1.0000x reference)
//
#include <hip/hip_runtime.h>

#define NN 24576
#define DD 32
#define KK 17
#define PP 20

#define WE ((DD - 1) * PP * KK * 20)   // padded W elems per chain: 31*20*340
#define SLICE_F4 85                    // one (d,p) padded slice = 17*20 floats = 85 float4

__device__ __forceinline__ float binom16(int k) {
    const float b[KK] = {1.f, 16.f, 120.f, 560.f, 1820.f, 4368.f, 8008.f, 11440.f,
                         12870.f, 11440.f, 8008.f, 4368.f, 1820.f, 560.f, 120.f, 16.f, 1.f};
    return b[k];
}

// t[k] = x^k * (1-x)^(16-k)   (binom folded into the weights by prep_w)
__device__ __forceinline__ void bernT(float x, float* t) {
    const float y = 1.0f - x;
    t[0] = 1.0f;
#pragma unroll
    for (int k = 1; k < KK; ++k) t[k] = t[k - 1] * x;
    float yp = y;
#pragma unroll
    for (int k = KK - 2; k >= 0; --k) {
        t[k] *= yp;
        yp *= y;
    }
}

// Build padded, binom-folded weight tables in workspace:
//  Wm[d,p,k,j20] = meanw[d,p,k,j] * binom[j]            (j<17, else 0)
//  Wv[d,p,k,j20] = exp(varw[d,p,k,j]) * sc2[j]*binom[j]^2
//  w0m[p,k] = meanw0[p,0,k] * binom[k]
//  w0v[p,k] = exp(varw0[p,0,k]) * sc2[k]*binom[k]^2
__global__ void prep_w(const float* __restrict__ mw, const float* __restrict__ vw,
                       const float* __restrict__ mw0, const float* __restrict__ vw0,
                       const float* __restrict__ psc,
                       float* __restrict__ Wm, float* __restrict__ Wv,
                       float* __restrict__ w0m, float* __restrict__ w0v) {
    int idx = blockIdx.x * blockDim.x + threadIdx.x;
    if (idx < WE) {
        const int j = idx % 20;
        const int k = (idx / 20) % KK;
        const int p = (idx / 340) % PP;
        const int dm1 = idx / (340 * PP);
        float v = 0.0f;
        if (j < KK)
            v = mw[(((size_t)dm1 * PP + p) * KK + k) * KK + j] * binom16(j);
        Wm[idx] = v;
    } else if (idx < 2 * WE) {
        const int i = idx - WE;
        const int j = i % 20;
        const int k = (i / 20) % KK;
        const int p = (i / 340) % PP;
        const int dm1 = i / (340 * PP);
        float v = 0.0f;
        if (j < KK) {
            const float s = psc[j] * binom16(j);
            v = expf(vw[(((size_t)dm1 * PP + p) * KK + k) * KK + j]) * s * s;
        }
        Wv[i] = v;
    } else if (idx < 2 * WE + PP * KK) {
        const int i = idx - 2 * WE;
        const int k = i % KK;
        w0m[i] = mw0[i] * binom16(k);
    } else if (idx < 2 * WE + 2 * PP * KK) {
        const int i = idx - 2 * WE - PP * KK;
        const int k = i % KK;
        const float s = psc[k] * binom16(k);
        w0v[i] = expf(vw0[i]) * s * s;
    }
}

// Transpose X [N,D] -> XT [D,N] so chain-kernel loads are lane-coalesced.
__global__ void transpose_x(const float* __restrict__ X, float* __restrict__ XT) {
    __shared__ float t[32][33];
    const int n0 = blockIdx.x * 32;
    for (int r = threadIdx.y; r < 32; r += 8)
        t[r][threadIdx.x] = X[(n0 + r) * DD + threadIdx.x];
    __syncthreads();
    for (int d = threadIdx.y; d < 32; d += 8)
        XT[d * NN + n0 + threadIdx.x] = t[threadIdx.x][d];
}

// Chain kernel with W staged in LDS (4 phases x 8 d-slices). Hot loop has
// ZERO scalar/global loads for W: uniform-address ds_read_b128 broadcast,
// covered by the 289-FMA block + co-resident waves. One (p,chain) per block.
__global__ __launch_bounds__(256, 6) void bez_chainL(
    const float* __restrict__ Xb, const int sx_d, const int sx_n,
    const float* __restrict__ w0m, const float* __restrict__ w0v,
    const float* __restrict__ Wm,  const float* __restrict__ Wv,  // padded [31,PP,17,20]
    const float* __restrict__ post_prec, const int* __restrict__ perm,
    float* __restrict__ out) {
    __shared__ __align__(16) float Wlds[8 * KK * 20];   // 10,880 B

    const bool VAR = (blockIdx.z != 0);
    const int p = blockIdx.y;
    const int n = blockIdx.x * blockDim.x + threadIdx.x;
    const int tid = threadIdx.x;
    const int* __restrict__ pp = perm + p * DD;
    const float4* __restrict__ Wsrc = (const float4*)(VAR ? Wv : Wm);

    float f[KK], t[KK];

    {   // d = 0
        const float x = Xb[pp[0] * sx_d + n * sx_n];
        bernT(x, t);
        if (VAR) {
#pragma unroll
            for (int k = 0; k < KK; ++k) t[k] *= t[k];
        }
        const float* __restrict__ w0 = (VAR ? w0v : w0m) + p * KK;
#pragma unroll
        for (int k = 0; k < KK; ++k) f[k] = w0[k] * t[k];
    }

    int d = 1;
#pragma unroll 1
    for (int phase = 0; phase < 4; ++phase) {
        const int nsl = (phase < 3) ? 8 : 7;

        __syncthreads();   // all waves done reading previous phase
        {
            float4* __restrict__ dst = (float4*)Wlds;
            const float4* __restrict__ src = Wsrc + ((size_t)(d - 1) * PP + p) * SLICE_F4;
            const int tot = nsl * SLICE_F4;
            for (int i = tid; i < tot; i += 256) {
                const int dd = i / SLICE_F4;
                const int r  = i - dd * SLICE_F4;
                dst[dd * SLICE_F4 + r] = src[(size_t)dd * (PP * SLICE_F4) + r];
            }
        }
        __syncthreads();

#pragma unroll 1
        for (int dd = 0; dd < nsl; ++dd, ++d) {
            // issue x-load early; consumed only after the FMA block
            const float x = Xb[pp[d] * sx_d + n * sx_n];

            const float* __restrict__ Wd = &Wlds[dd * (KK * 20)];

            float fn[KK];
            {   // row 0: init with mul (no mov+fma)
                const float4 a = *(const float4*)(Wd);
                const float4 b = *(const float4*)(Wd + 4);
                const float4 c = *(const float4*)(Wd + 8);
                const float4 e = *(const float4*)(Wd + 12);
                const float w16 = Wd[16];
                const float fk = f[0];
                fn[0] = fk * a.x;  fn[1] = fk * a.y;  fn[2] = fk * a.z;  fn[3] = fk * a.w;
                fn[4] = fk * b.x;  fn[5] = fk * b.y;  fn[6] = fk * b.z;  fn[7] = fk * b.w;
                fn[8] = fk * c.x;  fn[9] = fk * c.y;  fn[10] = fk * c.z; fn[11] = fk * c.w;
                fn[12] = fk * e.x; fn[13] = fk * e.y; fn[14] = fk * e.z; fn[15] = fk * e.w;
                fn[16] = fk * w16;
            }
#pragma unroll
            for (int k = 1; k < KK; ++k) {
                const float* __restrict__ row = Wd + k * 20;
                const float4 a = *(const float4*)(row);
                const float4 b = *(const float4*)(row + 4);
                const float4 c = *(const float4*)(row + 8);
                const float4 e = *(const float4*)(row + 12);
                const float w16 = row[16];
                const float fk = f[k];
                fn[0] = fmaf(fk, a.x, fn[0]);   fn[1] = fmaf(fk, a.y, fn[1]);
                fn[2] = fmaf(fk, a.z, fn[2]);   fn[3] = fmaf(fk, a.w, fn[3]);
                fn[4] = fmaf(fk, b.x, fn[4]);   fn[5] = fmaf(fk, b.y, fn[5]);
                fn[6] = fmaf(fk, b.z, fn[6]);   fn[7] = fmaf(fk, b.w, fn[7]);
                fn[8] = fmaf(fk, c.x, fn[8]);   fn[9] = fmaf(fk, c.y, fn[9]);
                fn[10] = fmaf(fk, c.z, fn[10]); fn[11] = fmaf(fk, c.w, fn[11]);
                fn[12] = fmaf(fk, e.x, fn[12]); fn[13] = fmaf(fk, e.y, fn[13]);
                fn[14] = fmaf(fk, e.z, fn[14]); fn[15] = fmaf(fk, e.w, fn[15]);
                fn[16] = fmaf(fk, w16, fn[16]);
            }

            bernT(x, t);
            if (VAR) {
#pragma unroll
                for (int j = 0; j < KK; ++j) t[j] *= t[j];
            }
#pragma unroll
            for (int j = 0; j < KK; ++j) f[j] = fn[j] * t[j];
        }
    }

    float s = 0.0f;
#pragma unroll
    for (int j = 0; j < KK; ++j) s += f[j];
    if (VAR) s /= post_prec[p];

    atomicAdd(&out[(VAR ? NN : 0) + n], s);
}

// ---------- round-2 fallback path (used only if workspace is tiny) ----------
__device__ __forceinline__ void bern17(float x, float* b) {
    const float y = 1.0f - x;
    b[0] = 1.0f;
#pragma unroll
    for (int k = 1; k < KK; ++k) b[k] = b[k - 1] * x;
    float yp = 1.0f;
#pragma unroll
    for (int k = KK - 1; k >= 0; --k) {
        b[k] = b[k] * yp * binom16(k);
        yp *= y;
    }
}

__global__ void prep_var(const float* __restrict__ varw, const float* __restrict__ varw0,
                         const float* __restrict__ prior_sc,
                         float* __restrict__ wv, float* __restrict__ wv0) {
    const int E1 = (DD - 1) * PP * KK * KK;
    int idx = blockIdx.x * blockDim.x + threadIdx.x;
    if (idx < E1) {
        int j = idx % KK;
        float s = prior_sc[j];
        wv[idx] = expf(varw[idx]) * s * s;
    } else if (idx < E1 + PP * KK) {
        int i = idx - E1;
        int k = i % KK;
        float s = prior_sc[k];
        wv0[i] = expf(varw0[i]) * s * s;
    }
}

__global__ __launch_bounds__(256, 4) void bez_chain2(
    const float* __restrict__ Xb, const int sx_d, const int sx_n,
    const float* __restrict__ mw0, const float* __restrict__ mW,
    const float* __restrict__ vw0, const float* __restrict__ vW,
    const float* __restrict__ post_prec, const int* __restrict__ perm,
    float* __restrict__ out) {
    const bool VAR = (blockIdx.z != 0);
    const int p = blockIdx.y;
    const int n = blockIdx.x * blockDim.x + threadIdx.x;
    const int* __restrict__ pp = perm + p * DD;
    const float* __restrict__ w0 = (VAR ? vw0 : mw0);
    const float* __restrict__ W  = (VAR ? vW  : mW);

    float f[KK], b[KK];
    {
        const int pd = pp[0];
        const float x = Xb[pd * sx_d + n * sx_n];
        bern17(x, b);
        if (VAR) {
#pragma unroll
            for (int k = 0; k < KK; ++k) b[k] *= b[k];
        }
        const float* __restrict__ w0p = w0 + p * KK;
#pragma unroll
        for (int k = 0; k < KK; ++k) f[k] = w0p[k] * b[k];
    }
    for (int d = 1; d < DD; ++d) {
        const int pd = pp[d];
        const float x = Xb[pd * sx_d + n * sx_n];
        bern17(x, b);
        if (VAR) {
#pragma unroll
            for (int k = 0; k < KK; ++k) b[k] *= b[k];
        }
        const float* __restrict__ Wd = W + ((size_t)(d - 1) * PP + p) * (KK * KK);
        float fn[KK];
#pragma unroll
        for (int j = 0; j < KK; ++j) fn[j] = 0.0f;
#pragma unroll
        for (int k = 0; k < KK; ++k) {
            const float fk = f[k];
#pragma unroll
            for (int j = 0; j < KK; ++j)
                fn[j] = fmaf(fk, Wd[k * KK + j], fn[j]);
        }
#pragma unroll
        for (int j = 0; j < KK; ++j) f[j] = fn[j] * b[j];
    }
    float s = 0.0f;
#pragma unroll
    for (int j = 0; j < KK; ++j) s += f[j];
    if (VAR) s /= post_prec[p];
    atomicAdd(&out[(VAR ? NN : 0) + n], s);
}
// ---------------------------------------------------------------------------

extern "C" void kernel_launch(void* const* d_in, const int* in_sizes, int n_in,
                              void* d_out, int out_size, void* d_ws, size_t ws_size,
                              hipStream_t stream) {
    const float* X    = (const float*)d_in[0];
    const float* mw0  = (const float*)d_in[1];
    const float* mw   = (const float*)d_in[2];
    const float* vw0  = (const float*)d_in[3];
    const float* vw   = (const float*)d_in[4];
    const float* psc  = (const float*)d_in[5];
    const float* ppr  = (const float*)d_in[6];
    const int*   perm = (const int*)d_in[7];
    float* out = (float*)d_out;

    hipMemsetAsync(d_out, 0, (size_t)out_size * sizeof(float), stream);

    // Workspace layout for the LDS path.
    const size_t xt_elems = (size_t)DD * NN;
    const size_t need_main = ((size_t)2 * WE + 2 * PP * KK + xt_elems) * sizeof(float);

    if (ws_size >= need_main) {
        float* Wm  = (float*)d_ws;             // [31,PP,17,20]
        float* Wv  = Wm + WE;                  // [31,PP,17,20]
        float* w0m = Wv + WE;                  // [PP,17]
        float* w0v = w0m + PP * KK;            // [PP,17]
        float* XT  = w0v + PP * KK;            // [D,N]

        const int E = 2 * WE + 2 * PP * KK;
        prep_w<<<dim3((E + 255) / 256), dim3(256), 0, stream>>>(mw, vw, mw0, vw0, psc,
                                                                Wm, Wv, w0m, w0v);
        transpose_x<<<dim3(NN / 32), dim3(32, 8), 0, stream>>>(X, XT);

        dim3 grid(NN / 256, PP, 2), blk(256);
        bez_chainL<<<grid, blk, 0, stream>>>(XT, NN, 1, w0m, w0v, Wm, Wv, ppr, perm, out);
        return;
    }

    // Fallback: round-2 path.
    const size_t wv_elems  = (size_t)(DD - 1) * PP * KK * KK;
    const size_t wv0_elems = (size_t)PP * KK;
    float* wv_b  = (float*)d_ws;
    float* wv0_b = wv_b + wv_elems;
    float* XT    = wv0_b + wv0_elems;

    const int E = (DD - 1) * PP * KK * KK + PP * KK;
    prep_var<<<dim3((E + 255) / 256), dim3(256), 0, stream>>>(vw, vw0, psc, wv_b, wv0_b);

    const bool use_xt = ((wv_elems + wv0_elems + xt_elems) * sizeof(float) <= ws_size);
    const float* Xb = X;
    int sx_d = 1, sx_n = DD;
    if (use_xt) {
        transpose_x<<<dim3(NN / 32), dim3(32, 8), 0, stream>>>(X, XT);
        Xb = XT; sx_d = NN; sx_n = 1;
    }
    dim3 grid(NN / 256, PP, 2), blk(256);
    bez_chain2<<<grid, blk, 0, stream>>>(Xb, sx_d, sx_n, mw0, mw, wv0_b, wv_b, ppr, perm, out);
}

// Round 5
// 286.846 us; speedup vs baseline: 43.2157x; 43.2157x over previous
//
#include <hip/hip_runtime.h>

#define NN 24576
#define DD 32
#define KK 17
#define PP 20

// Bernstein basis of order 16: b[k] = C(16,k) * x^k * (1-x)^(16-k)
__device__ __forceinline__ void bern17(float x, float* b) {
    const float binom[KK] = {1.f, 16.f, 120.f, 560.f, 1820.f, 4368.f, 8008.f, 11440.f,
                             12870.f, 11440.f, 8008.f, 4368.f, 1820.f, 560.f, 120.f, 16.f, 1.f};
    const float y = 1.0f - x;
    b[0] = 1.0f;
#pragma unroll
    for (int k = 1; k < KK; ++k) b[k] = b[k - 1] * x;   // b[k] = x^k
    float yp = 1.0f;
#pragma unroll
    for (int k = KK - 1; k >= 0; --k) {                  // multiply (1-x)^(16-k) * binom
        b[k] = b[k] * yp * binom[k];
        yp *= y;
    }
}

// Precompute var-chain weights: wv[d,p,k,j] = exp(varw[d,p,k,j]) * sc2[j]
//                               wv0[p,k]    = exp(varw0[p,0,k]) * sc2[k]
__global__ void prep_var(const float* __restrict__ varw, const float* __restrict__ varw0,
                         const float* __restrict__ prior_sc,
                         float* __restrict__ wv, float* __restrict__ wv0) {
    const int E1 = (DD - 1) * PP * KK * KK;
    int idx = blockIdx.x * blockDim.x + threadIdx.x;
    if (idx < E1) {
        int j = idx % KK;
        float s = prior_sc[j];
        wv[idx] = expf(varw[idx]) * s * s;
    } else if (idx < E1 + PP * KK) {
        int i = idx - E1;
        int k = i % KK;
        float s = prior_sc[k];
        wv0[i] = expf(varw0[i]) * s * s;
    }
}

// Transpose X [N,D] -> XT [D,N] so chain-kernel loads are lane-coalesced.
__global__ void transpose_x(const float* __restrict__ X, float* __restrict__ XT) {
    __shared__ float t[32][33];
    const int n0 = blockIdx.x * 32;
    for (int r = threadIdx.y; r < 32; r += 8)
        t[r][threadIdx.x] = X[(n0 + r) * DD + threadIdx.x];
    __syncthreads();
    for (int d = threadIdx.y; d < 32; d += 8)
        XT[d * NN + n0 + threadIdx.x] = t[threadIdx.x][d];
}

// One thread per (p, TWO n-points); one chain (mean or var) per block
// (blockIdx.z). The two chains share one W s_load stream (same schedule as
// the proven 28-VGPR kernel) so each ~200cy scalar-row-latency window is
// covered by 2x the FMAs. Simple scalar indexing -> known-good codegen.
__global__ __launch_bounds__(256, 4) void bez_chain2x2(
    const float* __restrict__ Xb,       // XT [DD,NN]
    const float* __restrict__ mw0,      // [PP,KK]
    const float* __restrict__ mW,       // [DD-1,PP,KK,KK]
    const float* __restrict__ vw0,      // [PP,KK] pre-scaled
    const float* __restrict__ vW,       // [DD-1,PP,KK,KK] pre-scaled
    const float* __restrict__ post_prec,// [PP]
    const int* __restrict__ perm,       // [PP,DD]
    float* __restrict__ out)            // [2*NN]
{
    const bool VAR = (blockIdx.z != 0);          // block-uniform branch
    const int p = blockIdx.y;
    const int n0 = blockIdx.x * 512 + threadIdx.x;
    const int n1 = n0 + 256;
    const int* __restrict__ pp = perm + p * DD;

    const float* __restrict__ w0 = (VAR ? vw0 : mw0);
    const float* __restrict__ W  = (VAR ? vW  : mW);

    float f0[KK], f1[KK], b0[KK], b1[KK];

    {
        const int pd = pp[0];
        const float x0 = Xb[pd * NN + n0];
        const float x1 = Xb[pd * NN + n1];
        bern17(x0, b0);
        bern17(x1, b1);
        if (VAR) {
#pragma unroll
            for (int k = 0; k < KK; ++k) { b0[k] *= b0[k]; b1[k] *= b1[k]; }
        }
        const float* __restrict__ w0p = w0 + p * KK;
#pragma unroll
        for (int k = 0; k < KK; ++k) { f0[k] = w0p[k] * b0[k]; f1[k] = w0p[k] * b1[k]; }
    }

    for (int d = 1; d < DD; ++d) {
        const int pd = pp[d];
        const float x0 = Xb[pd * NN + n0];
        const float x1 = Xb[pd * NN + n1];
        bern17(x0, b0);
        bern17(x1, b1);
        if (VAR) {
#pragma unroll
            for (int k = 0; k < KK; ++k) { b0[k] *= b0[k]; b1[k] *= b1[k]; }
        }

        const float* __restrict__ Wd = W + ((size_t)(d - 1) * PP + p) * (KK * KK);

        float fn0[KK], fn1[KK];
#pragma unroll
        for (int j = 0; j < KK; ++j) {               // k=0 row: init with mul
            const float w = Wd[j];
            fn0[j] = f0[0] * w;
            fn1[j] = f1[0] * w;
        }
#pragma unroll
        for (int k = 1; k < KK; ++k) {
            const float fk0 = f0[k];
            const float fk1 = f1[k];
#pragma unroll
            for (int j = 0; j < KK; ++j) {
                const float w = Wd[k * KK + j];      // uniform -> scalar load, ONE stream
                fn0[j] = fmaf(fk0, w, fn0[j]);
                fn1[j] = fmaf(fk1, w, fn1[j]);
            }
        }
#pragma unroll
        for (int j = 0; j < KK; ++j) { f0[j] = fn0[j] * b0[j]; f1[j] = fn1[j] * b1[j]; }
    }

    float s0 = 0.0f, s1 = 0.0f;
#pragma unroll
    for (int j = 0; j < KK; ++j) { s0 += f0[j]; s1 += f1[j]; }
    if (VAR) { const float ip = 1.0f / post_prec[p]; s0 *= ip; s1 *= ip; }

    const int base = VAR ? NN : 0;
    atomicAdd(&out[base + n0], s0);
    atomicAdd(&out[base + n1], s1);
}

// ---------- round-2 fallback (strided X, one n per thread) ----------
__global__ __launch_bounds__(256, 4) void bez_chain2(
    const float* __restrict__ Xb, const int sx_d, const int sx_n,
    const float* __restrict__ mw0, const float* __restrict__ mW,
    const float* __restrict__ vw0, const float* __restrict__ vW,
    const float* __restrict__ post_prec, const int* __restrict__ perm,
    float* __restrict__ out)
{
    const bool VAR = (blockIdx.z != 0);
    const int p = blockIdx.y;
    const int n = blockIdx.x * blockDim.x + threadIdx.x;
    const int* __restrict__ pp = perm + p * DD;
    const float* __restrict__ w0 = (VAR ? vw0 : mw0);
    const float* __restrict__ W  = (VAR ? vW  : mW);

    float f[KK], b[KK];
    {
        const int pd = pp[0];
        const float x = Xb[pd * sx_d + n * sx_n];
        bern17(x, b);
        if (VAR) {
#pragma unroll
            for (int k = 0; k < KK; ++k) b[k] *= b[k];
        }
        const float* __restrict__ w0p = w0 + p * KK;
#pragma unroll
        for (int k = 0; k < KK; ++k) f[k] = w0p[k] * b[k];
    }
    for (int d = 1; d < DD; ++d) {
        const int pd = pp[d];
        const float x = Xb[pd * sx_d + n * sx_n];
        bern17(x, b);
        if (VAR) {
#pragma unroll
            for (int k = 0; k < KK; ++k) b[k] *= b[k];
        }
        const float* __restrict__ Wd = W + ((size_t)(d - 1) * PP + p) * (KK * KK);
        float fn[KK];
#pragma unroll
        for (int j = 0; j < KK; ++j) fn[j] = 0.0f;
#pragma unroll
        for (int k = 0; k < KK; ++k) {
            const float fk = f[k];
#pragma unroll
            for (int j = 0; j < KK; ++j)
                fn[j] = fmaf(fk, Wd[k * KK + j], fn[j]);
        }
#pragma unroll
        for (int j = 0; j < KK; ++j) f[j] = fn[j] * b[j];
    }
    float s = 0.0f;
#pragma unroll
    for (int j = 0; j < KK; ++j) s += f[j];
    if (VAR) s /= post_prec[p];
    atomicAdd(&out[(VAR ? NN : 0) + n], s);
}
// --------------------------------------------------------------------

extern "C" void kernel_launch(void* const* d_in, const int* in_sizes, int n_in,
                              void* d_out, int out_size, void* d_ws, size_t ws_size,
                              hipStream_t stream) {
    const float* X    = (const float*)d_in[0];
    const float* mw0  = (const float*)d_in[1];
    const float* mw   = (const float*)d_in[2];
    const float* vw0  = (const float*)d_in[3];
    const float* vw   = (const float*)d_in[4];
    const float* psc  = (const float*)d_in[5];
    const float* ppr  = (const float*)d_in[6];
    const int*   perm = (const int*)d_in[7];
    float* out = (float*)d_out;

    const size_t wv_elems  = (size_t)(DD - 1) * PP * KK * KK;
    const size_t wv0_elems = (size_t)PP * KK;
    const size_t xt_elems  = (size_t)DD * NN;

    float* wv  = (float*)d_ws;                 // [D-1,P,K,K]
    float* wv0 = wv + wv_elems;                // [P,K]
    float* XT  = wv0 + wv0_elems;              // [D,N]

    const size_t need = (wv_elems + wv0_elems + xt_elems) * sizeof(float);
    const bool use_xt = (ws_size >= need);

    hipMemsetAsync(d_out, 0, (size_t)out_size * sizeof(float), stream);

    const int E = (DD - 1) * PP * KK * KK + PP * KK;
    prep_var<<<dim3((E + 255) / 256), dim3(256), 0, stream>>>(vw, vw0, psc, wv, wv0);

    if (use_xt) {
        transpose_x<<<dim3(NN / 32), dim3(32, 8), 0, stream>>>(X, XT);
        dim3 grid(NN / 512, PP, 2), blk(256);
        bez_chain2x2<<<grid, blk, 0, stream>>>(XT, mw0, mw, wv0, wv, ppr, perm, out);
    } else {
        dim3 grid(NN / 256, PP, 2), blk(256);
        bez_chain2<<<grid, blk, 0, stream>>>(X, 1, DD, mw0, mw, wv0, wv, ppr, perm, out);
    }
}